// Round 1
// baseline (129.703 us; speedup 1.0000x reference)
//
#include <hip/hip_runtime.h>
#include <cstdint>

#define R_SPHEREf 3.0f
#define NEARf 0.0f
#define FARf 100.0f
#define SECANT_STEPS 4
#define EPSf 1e-4f
#define R0f 1.0f
#define Hh 64
#define Lc 4
#define Sn 64

// tanh via: w2*tanh(x) = w2 - 2*w2 / (exp2(C*x)+1),  C = 2*log2(e).
#define C_HI 2.88539004325866699f   // float-nearest 2*log2(e)
#define C_LO 3.8519227871e-08f      // residual for fma correction

// x/y via v_rcp_f32 + 1 Newton step (~0.5 ulp, vs ~40cy fdiv sequence)
__device__ __forceinline__ float fastdiv(float a, float b) {
    float r = __builtin_amdgcn_rcpf(b);
    r = __builtin_fmaf(r, __builtin_fmaf(-b, r, 1.0f), r);
    return a * r;
}

__global__ __launch_bounds__(256) void manifold_render_kernel(
    const float* __restrict__ rays_o, const float* __restrict__ rays_d,
    const float* __restrict__ levels, const float* __restrict__ W1,
    const float* __restrict__ b1, const float* __restrict__ W2,
    const float* __restrict__ b2, float* __restrict__ out, int N)
{
    // per-wave {A2_h, B2_h, -2*w2_h, 0} quads (secant phase only now)
    __shared__ float4 abq[4][Hh];
    // per-wave transpose buffer for z*sigmoid terms; stride 33 dwords =>
    // writes (lanes=h, fixed s) and reads (lanes=s, fixed h) both hit
    // banks (h+s)%32: 2 lanes/bank = conflict-free.
    __shared__ float Pbuf[4][Hh][33];

    const int tid = threadIdx.x;
    const int wave = tid >> 6;
    const int lane = tid & 63;
    const int r = blockIdx.x * 4 + wave;
    if (r >= N) return;                  // no barriers anywhere: all LDS is wave-private

    const float b2v = b2[0];
    float lvl[Lc];
#pragma unroll
    for (int j = 0; j < Lc; ++j) lvl[j] = levels[j];

    const float ox = rays_o[3 * r], oy = rays_o[3 * r + 1], oz = rays_o[3 * r + 2];
    const float dx = rays_d[3 * r], dy = rays_d[3 * r + 1], dz = rays_d[3 * r + 2];

    // lane h = lane: per-ray linearization y_h(t) = A2 + t*B2 (exp2 domain)
    const float w1x = W1[lane], w1y = W1[Hh + lane], w1z = W1[2 * Hh + lane];
    const float w2lane = W2[lane];
    const float Ah = __builtin_fmaf(oz, w1z, __builtin_fmaf(oy, w1y,
                     __builtin_fmaf(ox, w1x, b1[lane])));
    const float Bh = __builtin_fmaf(dz, w1z, __builtin_fmaf(dy, w1y, dx * w1x));
    const float A2 = __builtin_fmaf(Ah, C_LO, Ah * C_HI);
    const float B2 = __builtin_fmaf(Bh, C_LO, Bh * C_HI);
    const float zq = -2.0f * w2lane;
    abq[wave][lane] = make_float4(A2, B2, zq, 0.0f);

    // W2SUM: butterfly sum of w2 across the wave
    float w2sum = w2lane;
#pragma unroll
    for (int m = 1; m < 64; m <<= 1) w2sum += __shfl_xor(w2sum, m);
    const float sbase = w2sum + b2v + R0f;

    // sphere bounds
    const float bq = ox * dx + oy * dy + oz * dz;
    const float cq = ox * ox + oy * oy + oz * oz - R_SPHEREf * R_SPHEREf;
    const float disc = bq * bq - cq;
    const bool hit = disc > 0.0f;
    const float sqv = __builtin_amdgcn_sqrtf(hit ? disc : 1.0f);
    const float d_near = fmaxf(-bq - sqv, NEARf);
    const float d_far  = fminf(-bq + sqv, FARf);
    const bool mask_bound = hit && (d_near < d_far);

    // ---- phase 1 (lane = hidden unit): sigmoid recurrence along the ray ----
    // e_{s+1} = e_s * g  with g = 2^(B2*delta)  =>  with u_s = (1+e_s)/z:
    //   z*sigmoid(y_s) = rcp(u_s),   u_{s+1} = u_s*g + (1-g)/z.
    // One fma + one rcp + one ds_write per element: no exp, no add, no z-mul,
    // no LDS broadcast. 63 chained fmas drift ~4e-6 relative — negligible.
    const float delta = (d_far - d_near) * (1.0f / 63.0f);
    const float zs = copysignf(fmaxf(fabsf(zq), 1e-30f), zq);   // keep rcp finite
    float rz = __builtin_amdgcn_rcpf(zs);
    rz = __builtin_fmaf(rz, __builtin_fmaf(-zs, rz, 1.0f), rz); // 1 NR
    const float e0 = __builtin_amdgcn_exp2f(__builtin_fmaf(d_near, B2, A2));
    const float g  = __builtin_amdgcn_exp2f(B2 * delta);
    const float cc = (1.0f - g) * rz;
    float u = __builtin_fmaf(e0, rz, rz);      // (1+e0)/z

    float* __restrict__ Pw = &Pbuf[wave][0][0];
    const int sl = lane & 31;
    float accA, accB;

    // chunk 0: samples 0..31
#pragma unroll
    for (int s = 0; s < 32; ++s) {
        Pw[lane * 33 + s] = __builtin_amdgcn_rcpf(u);
        u = __builtin_fmaf(u, g, cc);
    }
    {   // lane = sample (lanes 32..63 duplicate lanes 0..31: broadcast reads)
        float a0 = 0.f, a1 = 0.f, a2 = 0.f, a3 = 0.f;
#pragma unroll
        for (int h = 0; h < Hh; h += 4) {
            a0 += Pw[(h    ) * 33 + sl];
            a1 += Pw[(h + 1) * 33 + sl];
            a2 += Pw[(h + 2) * 33 + sl];
            a3 += Pw[(h + 3) * 33 + sl];
        }
        accA = (a0 + a1) + (a2 + a3);
    }
    // WAR fence: chunk-1 writes must not pass chunk-0 reads (same wave, in-order DS;
    // the waitcnt + memory clobber also pins the compiler's ordering)
    asm volatile("s_waitcnt lgkmcnt(0)" ::: "memory");
    // chunk 1: samples 32..63 (u has advanced 32 steps)
#pragma unroll
    for (int s = 0; s < 32; ++s) {
        Pw[lane * 33 + s] = __builtin_amdgcn_rcpf(u);
        u = __builtin_fmaf(u, g, cc);
    }
    {
        float a0 = 0.f, a1 = 0.f, a2 = 0.f, a3 = 0.f;
#pragma unroll
        for (int h = 0; h < Hh; h += 4) {
            a0 += Pw[(h    ) * 33 + sl];
            a1 += Pw[(h + 1) * 33 + sl];
            a2 += Pw[(h + 2) * 33 + sl];
            a3 += Pw[(h + 3) * 33 + sl];
        }
        accB = (a0 + a1) + (a2 + a3);
    }
    const float acc = (lane < 32) ? accA : accB;

    // ---- lane = sample index from here on (same layout as before) ----
    const float t = (float)lane * (1.0f / 63.0f);
    const float dsv = d_near * (1.0f - t) + d_far * t;
    const float x0 = ox + dx * dsv, x1 = oy + dy * dsv, x2 = oz + dz * dsv;
    const float nrm = __builtin_amdgcn_sqrtf(x0 * x0 + x1 * x1 + x2 * x2);
    const float scal = (acc + sbase) - nrm;
    const bool valid = nrm < R_SPHEREf;

    // neighbors (back sample of interval at lane j is sample j+1)
    const float scb = __shfl_down(scal, 1);
    const int validn = __shfl_down((int)valid, 1);
    const bool is_int = lane < (Sn - 1);

    // ind_lowest: first-occurrence argmin of sc_b over intervals
    float keyv = is_int ? scb : INFINITY;
    int keyi = lane;
#pragma unroll
    for (int m = 1; m < 64; m <<= 1) {
        float ov = __shfl_xor(keyv, m);
        int oi = __shfl_xor(keyi, m);
        if (ov < keyv || (ov == keyv && oi < keyi)) { keyv = ov; keyi = oi; }
    }
    const int ind_lowest = keyi;

    const bool inint_base = is_int && valid && (validn != 0);

    // per-level interval pick + secant init (uniform over all lanes)
    bool mintb[Lc], msec[Lc];
    float dinit[Lc];
    float g_dfs = 0.f, g_dbs = 0.f, g_sfs = 0.f, g_sbs = 0.f, g_dcur = 0.f, g_lr = 0.f;
    const int gl = lane >> 4;

#pragma unroll
    for (int lv = 0; lv < Lc; ++lv) {
        const float l = lvl[lv];
        unsigned long long bP = __ballot(is_int && (scb < l));
        unsigned long long bZ = __ballot(is_int && (scb == l));
        unsigned long long bI = __ballot(inint_base && (scal >= l) && (l >= scb));
        int ind_closest = bP ? __builtin_ctzll(bP)
                             : (bZ ? __builtin_ctzll(bZ) : (Sn - 2));
        bool mask_surface = (bI != 0ULL);
        int idx = mask_surface ? ind_closest : ind_lowest;

        float d_front = __shfl(dsv, idx);
        float d_back  = __shfl(dsv, idx + 1);
        float s_front = __shfl(scal, idx);
        float s_back  = __shfl(scal, idx + 1);

        bool mi = (s_front >= l) && (l >= s_back);
        float sd = s_front - s_back;
        bool vd = fabsf(sd) > EPSf;
        bool ms = mi && vd;
        float d_sec = fastdiv((l - s_back) * d_front + (s_front - l) * d_back,
                              vd ? sd : 1.0f);
        float di = ms ? d_sec : d_back;

        mintb[lv] = mi; msec[lv] = ms; dinit[lv] = di;
        if (gl == lv) {
            g_dfs = d_front; g_dbs = d_back; g_sfs = s_front; g_sbs = s_back;
            g_dcur = di; g_lr = l;
        }
    }

    // ---- secant refinement: 16 lanes per level, 4 hidden units per lane ----
    const float4* __restrict__ ab = &abq[wave][0];
    const int sub = lane & 15;
    float4 sq0 = ab[sub], sq1 = ab[sub + 16], sq2 = ab[sub + 32], sq3 = ab[sub + 48];

#pragma unroll
    for (int it = 0; it < SECANT_STEPS; ++it) {
        float mx0 = ox + g_dcur * dx, mx1 = oy + g_dcur * dy, mx2 = oz + g_dcur * dz;
        float mn = __builtin_amdgcn_sqrtf(mx0 * mx0 + mx1 * mx1 + mx2 * mx2);
        float part;
        {
            float y0 = __builtin_fmaf(g_dcur, sq0.y, sq0.x);
            float y1 = __builtin_fmaf(g_dcur, sq1.y, sq1.x);
            float y2 = __builtin_fmaf(g_dcur, sq2.y, sq2.x);
            float y3 = __builtin_fmaf(g_dcur, sq3.y, sq3.x);
            float r0 = __builtin_amdgcn_rcpf(__builtin_amdgcn_exp2f(y0) + 1.0f);
            float r1 = __builtin_amdgcn_rcpf(__builtin_amdgcn_exp2f(y1) + 1.0f);
            float r2 = __builtin_amdgcn_rcpf(__builtin_amdgcn_exp2f(y2) + 1.0f);
            float r3 = __builtin_amdgcn_rcpf(__builtin_amdgcn_exp2f(y3) + 1.0f);
            part = sq0.z * r0;
            part = __builtin_fmaf(sq1.z, r1, part);
            part = __builtin_fmaf(sq2.z, r2, part);
            part = __builtin_fmaf(sq3.z, r3, part);
        }
#pragma unroll
        for (int m = 1; m < 16; m <<= 1) part += __shfl_xor(part, m, 16);
        float s_mid = (part + sbase) - mn;
        bool mv = mn < R_SPHEREf;
        bool upf = (s_mid > g_lr) && mv;
        bool upb = (s_mid < g_lr) && mv;
        if (upf) { g_dfs = g_dcur; g_sfs = s_mid; }
        if (upb) { g_dbs = g_dcur; g_sbs = s_mid; }
        float sd2 = g_sfs - g_sbs;
        bool ok = fabsf(sd2) > EPSf;
        if (ok) g_dcur = fastdiv((g_lr - g_sbs) * g_dfs + (g_sfs - g_lr) * g_dbs, sd2);
    }

    // gather per-level results onto every lane
    float v0, v1, v2, v3;
    {
        float dc0 = __shfl(g_dcur, 0);
        float dc1 = __shfl(g_dcur, 16);
        float dc2 = __shfl(g_dcur, 32);
        float dc3 = __shfl(g_dcur, 48);
        v0 = msec[0] ? dc0 : dinit[0];
        v1 = msec[1] ? dc1 : dinit[1];
        v2 = msec[2] ? dc2 : dinit[2];
        v3 = msec[3] ? dc3 : dinit[3];
    }
    int m0 = mintb[0], m1 = mintb[1], m2 = mintb[2], m3 = mintb[3];
    int i0 = 0, i1 = 1, i2 = 2, i3 = 3;

    // stable sort of 4 by (value, original index) — 5-comparator network
#define CSWAP(va, ia, ma, vb, ib, mb)                                    \
    { bool sw = (vb < va) || (vb == va && ib < ia);                      \
      if (sw) { float tv = va; va = vb; vb = tv;                         \
                int ti = ia; ia = ib; ib = ti;                           \
                int tm = ma; ma = mb; mb = tm; } }
    CSWAP(v0, i0, m0, v1, i1, m1);
    CSWAP(v2, i2, m2, v3, i3, m3);
    CSWAP(v0, i0, m0, v2, i2, m2);
    CSWAP(v1, i1, m1, v3, i3, m3);
    CSWAP(v1, i1, m1, v2, i2, m2);
#undef CSWAP

    const long long NL = (long long)N * Lc;
    if (lane < Lc) {
        float dv = (lane == 0) ? v0 : (lane == 1) ? v1 : (lane == 2) ? v2 : v3;
        out[(long long)r * Lc + lane] = mask_bound ? dv : 0.0f;
    } else if (lane < 2 * Lc) {
        int k = lane - Lc;
        int mm = (k == 0) ? m0 : (k == 1) ? m1 : (k == 2) ? m2 : m3;
        out[NL + (long long)r * Lc + k] = (mm && mask_bound) ? 1.0f : 0.0f;
    }
}

extern "C" void kernel_launch(void* const* d_in, const int* in_sizes, int n_in,
                              void* d_out, int out_size, void* d_ws, size_t ws_size,
                              hipStream_t stream) {
    const float* rays_o = (const float*)d_in[0];
    const float* rays_d = (const float*)d_in[1];
    const float* levels = (const float*)d_in[2];
    const float* W1 = (const float*)d_in[3];
    const float* b1 = (const float*)d_in[4];
    const float* W2 = (const float*)d_in[5];
    const float* b2 = (const float*)d_in[6];
    float* out = (float*)d_out;

    const int N = in_sizes[0] / 3;          // B*R rays
    const int blocks = (N + 3) / 4;         // 4 waves (rays) per 256-thread block
    manifold_render_kernel<<<blocks, 256, 0, stream>>>(
        rays_o, rays_d, levels, W1, b1, W2, b2, out, N);
}

// Round 2
// 110.056 us; speedup vs baseline: 1.1785x; 1.1785x over previous
//
#include <hip/hip_runtime.h>
#include <cstdint>

#define R_SPHEREf 3.0f
#define NEARf 0.0f
#define FARf 100.0f
#define SECANT_STEPS 4
#define EPSf 1e-4f
#define R0f 1.0f
#define Hh 64
#define Lc 4
#define Sn 64

// tanh via: w2*tanh(x) = w2 + z/(1+exp2(C*x)),  z = -2*w2, C = 2*log2(e).
#define C_HI 2.88539004325866699f   // float-nearest 2*log2(e)
#define C_LO 3.8519227871e-08f      // residual for fma correction

// x/y via v_rcp_f32 + 1 Newton step (~0.5 ulp, vs ~40cy fdiv sequence)
__device__ __forceinline__ float fastdiv(float a, float b) {
    float r = __builtin_amdgcn_rcpf(b);
    r = __builtin_fmaf(r, __builtin_fmaf(-b, r, 1.0f), r);
    return a * r;
}

__global__ __launch_bounds__(256) void manifold_render_kernel(
    const float* __restrict__ rays_o, const float* __restrict__ rays_d,
    const float* __restrict__ levels, const float* __restrict__ W1,
    const float* __restrict__ b1, const float* __restrict__ W2,
    const float* __restrict__ b2, float* __restrict__ out, int N)
{
    // per-wave {A2_h, B2_h, rz_h, G_h} quads; rz = 1/z (z=-2w2), G = 2^(B2*8*delta)
    __shared__ float4 abq[4][Hh];

    const int tid = threadIdx.x;
    const int wave = tid >> 6;
    const int lane = tid & 63;
    const int r = blockIdx.x * 4 + wave;
    if (r >= N) return;                  // wave-private LDS rows: no barriers needed

    const float b2v = b2[0];
    float lvl[Lc];
#pragma unroll
    for (int j = 0; j < Lc; ++j) lvl[j] = levels[j];

    const float ox = rays_o[3 * r], oy = rays_o[3 * r + 1], oz = rays_o[3 * r + 2];
    const float dx = rays_d[3 * r], dy = rays_d[3 * r + 1], dz = rays_d[3 * r + 2];

    // sphere bounds (needed early: delta feeds G)
    const float bq = ox * dx + oy * dy + oz * dz;
    const float cq = ox * ox + oy * oy + oz * oz - R_SPHEREf * R_SPHEREf;
    const float disc = bq * bq - cq;
    const bool hit = disc > 0.0f;
    const float sqv = __builtin_amdgcn_sqrtf(hit ? disc : 1.0f);
    const float d_near = fmaxf(-bq - sqv, NEARf);
    const float d_far  = fminf(-bq + sqv, FARf);
    const bool mask_bound = hit && (d_near < d_far);
    const float delta = (d_far - d_near) * (1.0f / 63.0f);

    // lane h = lane: per-ray linearization y_h(t) = A2 + t*B2 (exp2 domain)
    const float w1x = W1[lane], w1y = W1[Hh + lane], w1z = W1[2 * Hh + lane];
    const float w2lane = W2[lane];
    const float Ah = __builtin_fmaf(oz, w1z, __builtin_fmaf(oy, w1y,
                     __builtin_fmaf(ox, w1x, b1[lane])));
    const float Bh = __builtin_fmaf(dz, w1z, __builtin_fmaf(dy, w1y, dx * w1x));
    const float A2 = __builtin_fmaf(Ah, C_LO, Ah * C_HI);
    const float B2 = __builtin_fmaf(Bh, C_LO, Bh * C_HI);
    const float zq = -2.0f * w2lane;
    const float zs = copysignf(fmaxf(fabsf(zq), 1e-30f), zq);   // keep rcp finite
    float rz = __builtin_amdgcn_rcpf(zs);
    rz = __builtin_fmaf(rz, __builtin_fmaf(-zs, rz, 1.0f), rz); // 1 NR
    const float Gh = __builtin_amdgcn_exp2f(B2 * (8.0f * delta));
    abq[wave][lane] = make_float4(A2, B2, rz, Gh);

    // W2SUM: butterfly sum of w2 across the wave
    float w2sum = w2lane;
#pragma unroll
    for (int m = 1; m < 64; m <<= 1) w2sum += __shfl_xor(w2sum, m);
    const float sbase = w2sum + b2v + R0f;

    // ---- main loop: lane = (hg = lane>>3 sample-phase, sl = lane&7) ----
    // each lane holds 8 hidden units h = hg' + 8j in registers and walks
    // 8 samples s = 8*i + sl via the fma recurrence v' = v*G + K
    // (v = rz*(1+e), 1/v = z*sigmoid). 3-shfl reduce per iter over hg;
    // lane keeps iter==hg so sample s ends on lane s exactly.
    const int hg = lane >> 3;
    const int sl = lane & 7;
    const float dsl = __builtin_fmaf((float)sl, delta, d_near);

    const float4* __restrict__ ab = &abq[wave][0];
    float v[8], Gr[8], K[8];
#pragma unroll
    for (int j = 0; j < 8; ++j) {
        const float4 q = ab[hg + 8 * j];
        const float y = fminf(__builtin_fmaf(dsl, q.y, q.x), 60.0f); // overflow guard
        const float e0 = __builtin_amdgcn_exp2f(y);
        v[j]  = __builtin_fmaf(e0, q.z, q.z);        // rz*(1+e0)
        Gr[j] = q.w;
        K[j]  = __builtin_fmaf(-q.z, q.w, q.z);      // rz*(1-G)
    }

    float mysum = 0.0f;
#pragma unroll
    for (int it = 0; it < 8; ++it) {
        if (it > 0) {
#pragma unroll
            for (int j = 0; j < 8; ++j) v[j] = __builtin_fmaf(v[j], Gr[j], K[j]);
        }
        // quad-rational: 1/v0+1/v1+1/v2+1/v3 = (n01*d23+n23*d01)/(d01*d23)
        const float n01 = v[0] + v[1], d01 = v[0] * v[1];
        const float n23 = v[2] + v[3], d23 = v[2] * v[3];
        const float numA = __builtin_fmaf(n23, d01, n01 * d23);
        const float denA = d01 * d23;
        const float n45 = v[4] + v[5], d45 = v[4] * v[5];
        const float n67 = v[6] + v[7], d67 = v[6] * v[7];
        const float numB = __builtin_fmaf(n67, d45, n45 * d67);
        const float denB = d45 * d67;
        float part = numA * __builtin_amdgcn_rcpf(denA);
        part = __builtin_fmaf(numB, __builtin_amdgcn_rcpf(denB), part);
        // reduce over the 8 hg-groups (bits 3..5 of lane)
        part += __shfl_xor(part, 8);
        part += __shfl_xor(part, 16);
        part += __shfl_xor(part, 32);
        if (it == hg) mysum = part;
    }

    // ---- lane = sample index from here on ----
    const float t = (float)lane * (1.0f / 63.0f);
    const float dsv = d_near * (1.0f - t) + d_far * t;
    const float x0 = ox + dx * dsv, x1 = oy + dy * dsv, x2 = oz + dz * dsv;
    const float nrm = __builtin_amdgcn_sqrtf(x0 * x0 + x1 * x1 + x2 * x2);
    const float scal = (mysum + sbase) - nrm;
    const bool valid = nrm < R_SPHEREf;

    // neighbors (back sample of interval at lane j is sample j+1)
    const float scb = __shfl_down(scal, 1);
    const int validn = __shfl_down((int)valid, 1);
    const bool is_int = lane < (Sn - 1);

    // ind_lowest: first-occurrence argmin of sc_b over intervals
    float keyv = is_int ? scb : INFINITY;
    int keyi = lane;
#pragma unroll
    for (int m = 1; m < 64; m <<= 1) {
        float ov = __shfl_xor(keyv, m);
        int oi = __shfl_xor(keyi, m);
        if (ov < keyv || (ov == keyv && oi < keyi)) { keyv = ov; keyi = oi; }
    }
    const int ind_lowest = keyi;

    const bool inint_base = is_int && valid && (validn != 0);

    // per-level interval pick + secant init (uniform over all lanes)
    bool mintb[Lc], msec[Lc];
    float dinit[Lc];
    float g_dfs = 0.f, g_dbs = 0.f, g_sfs = 0.f, g_sbs = 0.f, g_dcur = 0.f, g_lr = 0.f;
    const int gl = lane >> 4;

#pragma unroll
    for (int lv = 0; lv < Lc; ++lv) {
        const float l = lvl[lv];
        unsigned long long bP = __ballot(is_int && (scb < l));
        unsigned long long bZ = __ballot(is_int && (scb == l));
        unsigned long long bI = __ballot(inint_base && (scal >= l) && (l >= scb));
        int ind_closest = bP ? __builtin_ctzll(bP)
                             : (bZ ? __builtin_ctzll(bZ) : (Sn - 2));
        bool mask_surface = (bI != 0ULL);
        int idx = mask_surface ? ind_closest : ind_lowest;

        float d_front = __shfl(dsv, idx);
        float d_back  = __shfl(dsv, idx + 1);
        float s_front = __shfl(scal, idx);
        float s_back  = __shfl(scal, idx + 1);

        bool mi = (s_front >= l) && (l >= s_back);
        float sd = s_front - s_back;
        bool vd = fabsf(sd) > EPSf;
        bool ms = mi && vd;
        float d_sec = fastdiv((l - s_back) * d_front + (s_front - l) * d_back,
                              vd ? sd : 1.0f);
        float di = ms ? d_sec : d_back;

        mintb[lv] = mi; msec[lv] = ms; dinit[lv] = di;
        if (gl == lv) {
            g_dfs = d_front; g_dbs = d_back; g_sfs = s_front; g_sbs = s_back;
            g_dcur = di; g_lr = l;
        }
    }

    // ---- secant refinement: 16 lanes per level, 4 hidden units per lane ----
    const int sub = lane & 15;
    float4 sq0 = ab[sub], sq1 = ab[sub + 16], sq2 = ab[sub + 32], sq3 = ab[sub + 48];

#pragma unroll
    for (int it = 0; it < SECANT_STEPS; ++it) {
        float mx0 = ox + g_dcur * dx, mx1 = oy + g_dcur * dy, mx2 = oz + g_dcur * dz;
        float mn = __builtin_amdgcn_sqrtf(mx0 * mx0 + mx1 * mx1 + mx2 * mx2);
        float part;
        {
            float y0 = fminf(__builtin_fmaf(g_dcur, sq0.y, sq0.x), 60.0f);
            float y1 = fminf(__builtin_fmaf(g_dcur, sq1.y, sq1.x), 60.0f);
            float y2 = fminf(__builtin_fmaf(g_dcur, sq2.y, sq2.x), 60.0f);
            float y3 = fminf(__builtin_fmaf(g_dcur, sq3.y, sq3.x), 60.0f);
            float e0 = __builtin_amdgcn_exp2f(y0);
            float e1 = __builtin_amdgcn_exp2f(y1);
            float e2 = __builtin_amdgcn_exp2f(y2);
            float e3 = __builtin_amdgcn_exp2f(y3);
            float v0 = __builtin_fmaf(e0, sq0.z, sq0.z);
            float v1 = __builtin_fmaf(e1, sq1.z, sq1.z);
            float v2 = __builtin_fmaf(e2, sq2.z, sq2.z);
            float v3 = __builtin_fmaf(e3, sq3.z, sq3.z);
            // pair-rational: 1/v0+1/v1 = (v0+v1)/(v0*v1)
            float n01 = v0 + v1, d01 = v0 * v1;
            float n23 = v2 + v3, d23 = v2 * v3;
            part = n01 * __builtin_amdgcn_rcpf(d01);
            part = __builtin_fmaf(n23, __builtin_amdgcn_rcpf(d23), part);
        }
#pragma unroll
        for (int m = 1; m < 16; m <<= 1) part += __shfl_xor(part, m, 16);
        float s_mid = (part + sbase) - mn;
        bool mv = mn < R_SPHEREf;
        bool upf = (s_mid > g_lr) && mv;
        bool upb = (s_mid < g_lr) && mv;
        if (upf) { g_dfs = g_dcur; g_sfs = s_mid; }
        if (upb) { g_dbs = g_dcur; g_sbs = s_mid; }
        float sd2 = g_sfs - g_sbs;
        bool ok = fabsf(sd2) > EPSf;
        if (ok) g_dcur = fastdiv((g_lr - g_sbs) * g_dfs + (g_sfs - g_lr) * g_dbs, sd2);
    }

    // gather per-level results onto every lane
    float v0g, v1g, v2g, v3g;
    {
        float dc0 = __shfl(g_dcur, 0);
        float dc1 = __shfl(g_dcur, 16);
        float dc2 = __shfl(g_dcur, 32);
        float dc3 = __shfl(g_dcur, 48);
        v0g = msec[0] ? dc0 : dinit[0];
        v1g = msec[1] ? dc1 : dinit[1];
        v2g = msec[2] ? dc2 : dinit[2];
        v3g = msec[3] ? dc3 : dinit[3];
    }
    int m0 = mintb[0], m1 = mintb[1], m2 = mintb[2], m3 = mintb[3];
    int i0 = 0, i1 = 1, i2 = 2, i3 = 3;

    // stable sort of 4 by (value, original index) — 5-comparator network
#define CSWAP(va, ia, ma, vb, ib, mb)                                    \
    { bool sw = (vb < va) || (vb == va && ib < ia);                      \
      if (sw) { float tv = va; va = vb; vb = tv;                         \
                int ti = ia; ia = ib; ib = ti;                           \
                int tm = ma; ma = mb; mb = tm; } }
    CSWAP(v0g, i0, m0, v1g, i1, m1);
    CSWAP(v2g, i2, m2, v3g, i3, m3);
    CSWAP(v0g, i0, m0, v2g, i2, m2);
    CSWAP(v1g, i1, m1, v3g, i3, m3);
    CSWAP(v1g, i1, m1, v2g, i2, m2);
#undef CSWAP

    const long long NL = (long long)N * Lc;
    if (lane < Lc) {
        float dv = (lane == 0) ? v0g : (lane == 1) ? v1g : (lane == 2) ? v2g : v3g;
        out[(long long)r * Lc + lane] = mask_bound ? dv : 0.0f;
    } else if (lane < 2 * Lc) {
        int k = lane - Lc;
        int mm = (k == 0) ? m0 : (k == 1) ? m1 : (k == 2) ? m2 : m3;
        out[NL + (long long)r * Lc + k] = (mm && mask_bound) ? 1.0f : 0.0f;
    }
}

extern "C" void kernel_launch(void* const* d_in, const int* in_sizes, int n_in,
                              void* d_out, int out_size, void* d_ws, size_t ws_size,
                              hipStream_t stream) {
    const float* rays_o = (const float*)d_in[0];
    const float* rays_d = (const float*)d_in[1];
    const float* levels = (const float*)d_in[2];
    const float* W1 = (const float*)d_in[3];
    const float* b1 = (const float*)d_in[4];
    const float* W2 = (const float*)d_in[5];
    const float* b2 = (const float*)d_in[6];
    float* out = (float*)d_out;

    const int N = in_sizes[0] / 3;          // B*R rays
    const int blocks = (N + 3) / 4;         // 4 waves (rays) per 256-thread block
    manifold_render_kernel<<<blocks, 256, 0, stream>>>(
        rays_o, rays_d, levels, W1, b1, W2, b2, out, N);
}